// Round 18
// baseline (72.103 us; speedup 1.0000x reference)
//
#include <hip/hip_runtime.h>
#include <hip/hip_bf16.h>

#define LSEQ 2048
#define BB   2048
#define TT   7
#define NFLD 17   // SoA fields: [0..6] vn, [7..13] rn, [14] sc, [15] mc, [16] Lmass

typedef float f4 __attribute__((ext_vector_type(4)));

// Load 7 floats from a 4B-aligned row as two overlapping dwordx4 loads.
__device__ __forceinline__ void ld7(const float* __restrict__ p, float* e) {
  f4 lo, hi;
  __builtin_memcpy(&lo, p, 16);
  __builtin_memcpy(&hi, p + 3, 16);
  e[0] = lo.x; e[1] = lo.y; e[2] = lo.z; e[3] = lo.w;
  e[4] = hi.y; e[5] = hi.z; e[6] = hi.w;
}

// ---------------------------------------------------------------------------
// Rank-1 chunk decomposition, v6.1 (R17 + OOB fix: batch base must be
// (bid*256) & (BB-1), not bid*256 — R17's fault).
// P_c = u s v^T, s = 1^T P 1.
// R10..R16 invariant: effective BW pins at ~2 TB/s for ALL occupancies ->
// L1 line-transaction wall from 28B-stride em loads (each dwordx4 spans ~29
// cache lines). Fix: FORWARD blocks stage em through wave-private LDS tiles
// (4 steps x 64 b = 7KB/wave) with contiguous 16B/lane loads (~7x fewer line
// transactions), T14 split (issue-early / ds_write-late), double-buffered,
// NO barriers in the loop (tile is wave-private; R11's per-step
// __syncthreads was the killer there, not the staging). Flags stay direct
// (4B stride = coalesced). BACKWARD blocks: R15's proven direct-load
// dual-stream u-direction (12 steps, rows L2-hot), same launch.
// NOTE: no asm-load rings (R14 fault); no min-wave launch_bounds (R5/R7).
// ---------------------------------------------------------------------------
template<int KCH>
__global__ __launch_bounds__(256)
void crf_chunk_kernel(const float* __restrict__ em,
                      const int*   __restrict__ tags,
                      const int*   __restrict__ qmask,
                      const int*   __restrict__ mask,
                      const float* __restrict__ self_t,
                      const float* __restrict__ other_t,
                      float* __restrict__ recs) {
  constexpr int CC   = LSEQ / KCH;      // 32
  constexpr int NG   = KCH * BB;
  constexpr int NGH  = NG / 2;
  constexpr int NB   = 12;              // backward steps for u direction
  constexpr int NT   = CC / 4;          // 4-step tiles per chunk
  constexpr int NFWD = NG / 256;        // forward blocks

  __shared__ float sE[2][49];           // exp(transitions)
  __shared__ float sT[2][49];           // raw transitions
  __shared__ float sTileF[2][4 * 256 * TT];   // 2 x 28KB em tiles

  int tid = threadIdx.x;
  if (tid < 49) {
    float sv = self_t[tid], ov = other_t[tid];
    sE[0][tid] = __expf(sv); sE[1][tid] = __expf(ov);
    sT[0][tid] = sv;         sT[1][tid] = ov;
  }
  __syncthreads();                      // only barrier in the kernel

  float Es[49];                         // SGPR-resident when cont uniform
  int loadedCont = -1;
  auto loadEs = [&](int cf) {
#pragma unroll
    for (int k = 0; k < 49; ++k)
      Es[k] = __int_as_float(
          __builtin_amdgcn_readfirstlane(__float_as_int(sE[cf][k])));
    loadedCont = cf;
  };

  int bid = blockIdx.x;
  if (bid < NFWD) {
    // ================= forward: LDS-tiled, 1 chunk/thread =================
    int lane = tid & 63, wv = tid >> 6;
    int g = bid * 256 + tid;
    int b = g & (BB - 1);
    int b0 = (bid * 256) & (BB - 1);    // block's batch base (R17 fix!)
    int c = g >> 11;                    // uniform per block (256 | 2048)
    int i_base = c * CC;

    float v[7] = {1.f,1.f,1.f,1.f,1.f,1.f,1.f};
    float sc = 0.f, Lv = 0.f;
    int mc = 0, tp, qp;
    if (c == 0) { mc = mask[b]; tp = tags[b]; qp = qmask[b]; }
    else { size_t pb = (size_t)(i_base - 1) * BB + b; tp = tags[pb]; qp = qmask[pb]; }

    // 4-row tile = 4 x 1792B wave-segments = 448 f4 per wave = 7 f4/lane.
    auto LOADT = [&](int k, f4* rg) {
#pragma unroll
      for (int r = 0; r < 7; ++r) {
        int slot = r * 64 + lane;
        int row = slot / 112, wi = slot - row * 112;
        const float* p = em + ((size_t)(i_base + k * 4 + row) * BB
                               + (size_t)b0 + (size_t)wv * 64) * TT;
        __builtin_memcpy(&rg[r], p + wi * 4, 16);   // 16B-aligned segments
      }
    };
    auto WRITET = [&](int bf, const f4* rg) {
#pragma unroll
      for (int r = 0; r < 7; ++r) {
        int slot = r * 64 + lane;
        int row = slot / 112, wi = slot - row * 112;
        __builtin_memcpy(&sTileF[bf][(row * 448 + wv * 112 + wi) * 4], &rg[r], 16);
      }
    };
    auto LDFLAGS = [&](int k, int* tg, int* qm, int* mi) {
#pragma unroll
      for (int s = 0; s < 4; ++s) {
        size_t base = (size_t)(i_base + k * 4 + s) * BB + b;
        tg[s] = tags[base]; qm[s] = qmask[base]; mi[s] = mask[base];
      }
    };

    f4 rg[7];
    LOADT(0, rg); WRITET(0, rg);
    int tg[4], qm[4], mi[4];
    LDFLAGS(0, tg, qm, mi);
    int buf = 0;

    for (int k = 0; k < NT; ++k) {
      bool more = (k + 1 < NT);                    // wave-uniform
      if (more) LOADT(k + 1, rg);                  // issue-early (T14)
      int tgn[4], qmn[4], min_[4];
      if (more) LDFLAGS(k + 1, tgn, qmn, min_);

      const float* lb = sTileF[buf];
#pragma unroll
      for (int s = 0; s < 4; ++s) {
        const float* e = lb + s * 1792 + wv * 448 + lane * 7;
        int m = (c == 0 && k == 0 && s == 0) ? 0 : mi[s];  // boundary step

        int cont = (qm[s] != qp) ? 1 : 0;
        int cf = __builtin_amdgcn_readfirstlane(cont);
        bool uni = __all(cont == cf);
        float ee[7];
#pragma unroll
        for (int t = 0; t < 7; ++t) ee[t] = __expf(e[t]);
        float etag = e[0];
#pragma unroll
        for (int t = 1; t < 7; ++t) etag = (tg[s] == t) ? e[t] : etag;
        float ttag = sT[cont][tp * 7 + tg[s]];
        if (m) { sc += ttag + etag; ++mc; }
        tp = tg[s]; qp = qm[s];

        float a[7] = {0.f,0.f,0.f,0.f,0.f,0.f,0.f};
        if (uni) {
          if (cf != loadedCont) loadEs(cf);
#pragma unroll
          for (int r = 0; r < 7; ++r) {
            float vr = v[r];
#pragma unroll
            for (int t = 0; t < 7; ++t) a[t] = fmaf(vr, Es[r*7+t], a[t]);
          }
        } else {
          loadedCont = -1;
#pragma unroll
          for (int r = 0; r < 7; ++r) {
            float vr = v[r];
#pragma unroll
            for (int t = 0; t < 7; ++t) a[t] = fmaf(vr, sE[cont][r*7+t], a[t]);
          }
        }
#pragma unroll
        for (int t = 0; t < 7; ++t) v[t] = m ? a[t] * ee[t] : v[t];
      }

      if (k & 1) {                                 // renorm every 8 steps
        float ss = v[0]+v[1]+v[2]+v[3]+v[4]+v[5]+v[6];
        Lv += logf(ss);
        float inv = 1.0f / ss;
#pragma unroll
        for (int t = 0; t < 7; ++t) v[t] *= inv;
      }

      if (more) {
        WRITET(buf ^ 1, rg);                       // write-late (T14)
#pragma unroll
        for (int s = 0; s < 4; ++s) { tg[s]=tgn[s]; qm[s]=qmn[s]; mi[s]=min_[s]; }
      }
      buf ^= 1;
    }

    float ss = v[0]+v[1]+v[2]+v[3]+v[4]+v[5]+v[6];
    float inv = 1.0f / ss;
#pragma unroll
    for (int t = 0; t < 7; ++t) recs[(size_t)t * NG + g] = v[t] * inv;
    recs[(size_t)14 * NG + g] = sc;
    recs[(size_t)15 * NG + g] = (float)mc;
    recs[(size_t)16 * NG + g] = Lv + logf(ss);     // Lmass = log(1^T P 1)
  } else {
    // ============ backward: u direction, 2 streams, direct loads ==========
    int p = (bid - NFWD) * 256 + tid;              // pair id in [0, NGH)
    int b  = p & (BB - 1);
    int c1 = p >> 11;
    int c2 = c1 + KCH / 2;
    int g1 = p, g2 = p + NGH;

    float rA[7], rB[7];
#pragma unroll
    for (int t = 0; t < 7; ++t) { rA[t] = 1.f; rB[t] = 1.f; }
    int iloA = (c1 == 0) ? 1 : c1 * CC;
    int iloB = c2 * CC;

    auto LDbA = [&](int s, float* e, int& q, int& q1, int& mi2) {
      size_t base = (size_t)(iloA + NB - 1 - s) * BB + b;   // i >= 1
      ld7(em + base * TT, e);
      q = qmask[base]; q1 = qmask[base - BB]; mi2 = mask[base];
    };
    auto LDbB = [&](int s, float* e, int& q, int& q1, int& mi2) {
      size_t base = (size_t)(iloB + NB - 1 - s) * BB + b;
      ld7(em + base * TT, e);
      q = qmask[base]; q1 = qmask[base - BB]; mi2 = mask[base];
    };

    auto STEPB = [&](const float* e, int q, int q1, int mi2, float* r) {
      int cont = (q != q1) ? 1 : 0;
      int cf = __builtin_amdgcn_readfirstlane(cont);
      bool uni = __all(cont == cf);
      float ee[7];
#pragma unroll
      for (int t = 0; t < 7; ++t) ee[t] = __expf(e[t]);
      float tmp[7];
#pragma unroll
      for (int t = 0; t < 7; ++t) tmp[t] = ee[t] * r[t];
      float a[7] = {0.f,0.f,0.f,0.f,0.f,0.f,0.f};
      if (uni) {
        if (cf != loadedCont) loadEs(cf);
#pragma unroll
        for (int t = 0; t < 7; ++t) {
          float tt = tmp[t];
#pragma unroll
          for (int s2 = 0; s2 < 7; ++s2) a[s2] = fmaf(tt, Es[s2*7+t], a[s2]);
        }
      } else {
        loadedCont = -1;
#pragma unroll
        for (int t = 0; t < 7; ++t) {
          float tt = tmp[t];
#pragma unroll
          for (int s2 = 0; s2 < 7; ++s2) a[s2] = fmaf(tt, sE[cont][s2*7+t], a[s2]);
        }
      }
#pragma unroll
      for (int s2 = 0; s2 < 7; ++s2) r[s2] = mi2 ? a[s2] : r[s2];
    };

    float eA0[7], eA1[7], eB0[7], eB1[7];
    int qA0, q1A0, mA0, qA1, q1A1, mA1;
    int qB0, q1B0, mB0, qB1, q1B1, mB1;
    LDbA(0, eA0, qA0, q1A0, mA0);
    LDbB(0, eB0, qB0, q1B0, mB0);

    for (int j = 0; j < NB; ++j) {
      bool more = (j + 1 < NB);
      if (more) {
        LDbA(j + 1, eA1, qA1, q1A1, mA1);
        LDbB(j + 1, eB1, qB1, q1B1, mB1);
      }
      STEPB(eA0, qA0, q1A0, mA0, rA);
      STEPB(eB0, qB0, q1B0, mB0, rB);
      if (j == 5) {                                // overflow guard
        float sA = rA[0]+rA[1]+rA[2]+rA[3]+rA[4]+rA[5]+rA[6];
        float sB = rB[0]+rB[1]+rB[2]+rB[3]+rB[4]+rB[5]+rB[6];
        float iA2 = 1.0f / sA, iB2 = 1.0f / sB;
#pragma unroll
        for (int t = 0; t < 7; ++t) { rA[t] *= iA2; rB[t] *= iB2; }
      }
      if (more) {
#pragma unroll
        for (int t = 0; t < 7; ++t) { eA0[t] = eA1[t]; eB0[t] = eB1[t]; }
        qA0 = qA1; q1A0 = q1A1; mA0 = mA1;
        qB0 = qB1; q1B0 = q1B1; mB0 = mB1;
      }
    }
    float sA = rA[0]+rA[1]+rA[2]+rA[3]+rA[4]+rA[5]+rA[6];
    float sB = rB[0]+rB[1]+rB[2]+rB[3]+rB[4]+rB[5]+rB[6];
    float iA2 = 1.0f / sA, iB2 = 1.0f / sB;
#pragma unroll
    for (int t = 0; t < 7; ++t) {
      recs[(size_t)(7 + t) * NG + g1] = rA[t] * iA2;
      recs[(size_t)(7 + t) * NG + g2] = rB[t] * iB2;
    }
  }
}

// ---------------------------------------------------------------------------
// Kernel 2: flat-parallel junction terms + per-block tree reduction.
// ---------------------------------------------------------------------------
template<int KCH>
__global__ __launch_bounds__(256)
void crf_junction_kernel(const float* __restrict__ recs,
                         const float* __restrict__ em,
                         const int*   __restrict__ tags,
                         const float* __restrict__ start_t,
                         const float* __restrict__ end_t,
                         float* __restrict__ partials) {
  constexpr int NG = KCH * BB;
  int tid = threadIdx.x;
  int g = blockIdx.x * 256 + tid;
  int b = g & (BB - 1);
  int c = g >> 11;
  float rn[7];
#pragma unroll
  for (int t = 0; t < 7; ++t) rn[t] = recs[(size_t)(7 + t) * NG + g];
  float term = recs[(size_t)14 * NG + g] - recs[(size_t)16 * NG + g];
  float dot = 0.f;
  if (c == 0) {
    float e0[7], st[7];
#pragma unroll
    for (int t = 0; t < 7; ++t) { e0[t] = em[(size_t)b * TT + t]; st[t] = start_t[t]; }
#pragma unroll
    for (int t = 0; t < 7; ++t) dot = fmaf(__expf(st[t] + e0[t]), rn[t], dot);
    int tg0 = tags[b];
    float em0t = e0[0], stt = st[0];
#pragma unroll
    for (int t = 1; t < 7; ++t) {
      em0t = (tg0 == t) ? e0[t] : em0t;
      stt  = (tg0 == t) ? st[t] : stt;
    }
    term += stt + em0t;
  } else {
#pragma unroll
    for (int t = 0; t < 7; ++t)
      dot = fmaf(recs[(size_t)t * NG + (g - BB)], rn[t], dot);
  }
  term -= logf(dot);
  if (c == KCH - 1) {
    float fz = 0.f;
#pragma unroll
    for (int t = 0; t < 7; ++t)
      fz = fmaf(recs[(size_t)t * NG + g], __expf(end_t[t]), fz);
    term -= logf(fz);
    float mcf = 0.f;
    for (int cc = 0; cc < KCH; ++cc)
      mcf += recs[(size_t)15 * NG + (size_t)cc * BB + b];
    int se = (int)mcf - 1;
    int te = tags[(size_t)se * BB + b];
    term += end_t[te];
  }
  __shared__ float red[256];
  red[tid] = term;
  __syncthreads();
  for (int off = 128; off > 0; off >>= 1) {
    if (tid < off) red[tid] += red[tid + off];
    __syncthreads();
  }
  if (tid == 0) partials[blockIdx.x] = red[0];
}

// ---------------------------------------------------------------------------
// Kernel 3: deterministic tree-reduce of the block partials.
// ---------------------------------------------------------------------------
__global__ __launch_bounds__(1024)
void crf_reduce_kernel(const float* __restrict__ partials, int n,
                       float* __restrict__ out) {
  __shared__ float s[1024];
  int t = threadIdx.x;
  float v = 0.f;
  for (int i = t; i < n; i += 1024) v += partials[i];
  s[t] = v;
  __syncthreads();
  for (int off = 512; off > 0; off >>= 1) {
    if (t < off) s[t] += s[t + off];
    __syncthreads();
  }
  if (t == 0) out[0] = s[0];
}

extern "C" void kernel_launch(void* const* d_in, const int* in_sizes, int n_in,
                              void* d_out, int out_size, void* d_ws, size_t ws_size,
                              hipStream_t stream) {
  const float* em      = (const float*)d_in[0];
  const int*   tags    = (const int*)d_in[1];
  const int*   qmask   = (const int*)d_in[2];
  const int*   mask    = (const int*)d_in[3];
  const float* start_t = (const float*)d_in[4];
  const float* end_t   = (const float*)d_in[5];
  const float* self_t  = (const float*)d_in[6];
  const float* other_t = (const float*)d_in[7];

  float* recs = (float*)d_ws;

  constexpr int KCH = 64;     // CC=32; ws need ~8.9 MB
  constexpr int NG  = KCH * BB;
  float* partials = recs + (size_t)NFLD * NG;

  int fwd_blocks = NG / 256;          // 512
  int bwd_blocks = (NG / 2) / 256;    // 256
  crf_chunk_kernel<KCH><<<fwd_blocks + bwd_blocks, 256, 0, stream>>>(
      em, tags, qmask, mask, self_t, other_t, recs);
  crf_junction_kernel<KCH><<<NG / 256, 256, 0, stream>>>(
      recs, em, tags, start_t, end_t, partials);
  crf_reduce_kernel<<<1, 1024, 0, stream>>>(partials, NG / 256, (float*)d_out);
}

// Round 19
// 55.359 us; speedup vs baseline: 1.3025x; 1.3025x over previous
//
#include <hip/hip_runtime.h>
#include <hip/hip_bf16.h>

#define LSEQ 2048
#define BB   2048
#define TT   7
#define NFLD 17   // SoA fields: [0..6] vn, [7..13] rn, [14] sc, [15] mc, [16] Lmass

typedef float f4 __attribute__((ext_vector_type(4)));

// Load 7 floats from a 4B-aligned row as two overlapping dwordx4 loads.
__device__ __forceinline__ void ld7(const float* __restrict__ p, float* e) {
  f4 lo, hi;
  __builtin_memcpy(&lo, p, 16);
  __builtin_memcpy(&hi, p + 3, 16);
  e[0] = lo.x; e[1] = lo.y; e[2] = lo.z; e[3] = lo.w;
  e[4] = hi.y; e[5] = hi.z; e[6] = hi.w;
}

// ---------------------------------------------------------------------------
// Rank-1 chunk decomposition, v7 (= R15 dual-stream structure + convergent-
// free inner loops).
// P_c = u s v^T, s = 1^T P 1.
//   forward (CC=32 steps): v <- (v.E) o ee -> vn, Lmass, gold sc, mask count.
//   backward (NB=12 steps): u DIRECTION only (contraction ~0.1/step).
// R18 falsified the L1-transaction theory (coalesced LDS tiles were SLOWER).
// New theory: per-step readfirstlane/__all are convergent -> compiler cannot
// hoist next-step loads across them -> depth-1 serial latency every step
// (explains R9/R12/R13 collapsed prefetch rings). Fix: per-chunk qmask
// PRESCAN (replaces main-loop qmask loads) + ONE __any per chunk; fast path
// (cont==0 everywhere) is branch-free with ZERO convergent ops in the loop,
// E in SGPRs; slow path = R15 loop verbatim.
// NOTE: no asm-load rings (R14 fault); no min-wave launch_bounds (R5/R7).
// ---------------------------------------------------------------------------
template<int KCH>
__global__ __launch_bounds__(256)
void crf_chunk_kernel(const float* __restrict__ em,
                      const int*   __restrict__ tags,
                      const int*   __restrict__ qmask,
                      const int*   __restrict__ mask,
                      const float* __restrict__ self_t,
                      const float* __restrict__ other_t,
                      float* __restrict__ recs) {
  constexpr int CC  = LSEQ / KCH;   // 32
  constexpr int NG  = KCH * BB;
  constexpr int NGH = NG / 2;
  constexpr int NB  = 12;           // backward steps for u direction
  __shared__ float sE[2][49];       // exp(transitions)
  __shared__ float sT[2][49];       // raw transitions
  int tid = threadIdx.x;
  if (tid < 49) {
    float sv = self_t[tid], ov = other_t[tid];
    sE[0][tid] = __expf(sv); sE[1][tid] = __expf(ov);
    sT[0][tid] = sv;         sT[1][tid] = ov;
  }
  __syncthreads();

  int role = tid >> 7;              // wave-uniform: 0 = forward, 1 = backward
  int p = blockIdx.x * 128 + (tid & 127);   // pair id
  int b  = p & (BB - 1);
  int c1 = p >> 11;                 // uniform per block (128 | 2048)
  int c2 = c1 + KCH / 2;
  int g1 = p, g2 = p + NGH;

  float Es[49];                     // SGPR-resident via readfirstlane
  int loadedCont = -1;
  auto loadEs = [&](int cf) {
#pragma unroll
    for (int k = 0; k < 49; ++k)
      Es[k] = __int_as_float(
          __builtin_amdgcn_readfirstlane(__float_as_int(sE[cf][k])));
    loadedCont = cf;
  };

  if (role == 0) {
    // =============== forward: vn, Lmass, gold score (2 streams) ===========
    float vA[7], vB[7];
#pragma unroll
    for (int t = 0; t < 7; ++t) { vA[t] = 1.f; vB[t] = 1.f; }
    float scA = 0.f, scB = 0.f, LvA = 0.f, LvB = 0.f;
    int mcA = 0, mcB = 0, tpA, qpA, tpB, qpB;
    int iA = c1 * CC, iB = c2 * CC;
    if (c1 == 0) { mcA = mask[b]; tpA = tags[b]; qpA = qmask[b]; }
    else { size_t pb = (size_t)(iA - 1) * BB + b; tpA = tags[pb]; qpA = qmask[pb]; }
    { size_t pb = (size_t)(iB - 1) * BB + b; tpB = tags[pb]; qpB = qmask[pb]; }

    // ---- prescan: does cont flip anywhere in either chunk? ----
    int afA = 0, afB = 0;
    {
      int prevA = qpA, prevB = qpB;
#pragma unroll 8
      for (int s = 0; s < CC; ++s) {
        int qa = qmask[(size_t)(iA + s) * BB + b];
        int qb = qmask[(size_t)(iB + s) * BB + b];
        afA |= (qa != prevA); prevA = qa;
        afB |= (qb != prevB); prevB = qb;
      }
    }
    bool fast = !__any(afA | afB);    // ONE convergent op per chunk pair

    auto LDfA = [&](int s, float* e, int& tg, int& mi) {
      size_t base = (size_t)(iA + s) * BB + b;
      ld7(em + base * TT, e);
      tg = tags[base]; mi = mask[base];
    };
    auto LDfB = [&](int s, float* e, int& tg, int& mi) {
      size_t base = (size_t)(iB + s) * BB + b;
      ld7(em + base * TT, e);
      tg = tags[base]; mi = mask[base];
    };

    if (fast) {
      // ---- branch-free, convergent-free inner loop; cont == 0 ----
      loadEs(0);
      auto FSTEP = [&](const float* e, int tg, int mi,
                       float* v, float& sc, int& mc, int& tp) {
        float ee[7];
#pragma unroll
        for (int t = 0; t < 7; ++t) ee[t] = __expf(e[t]);
        float etag = e[0];
#pragma unroll
        for (int t = 1; t < 7; ++t) etag = (tg == t) ? e[t] : etag;
        float ttag = sT[0][tp * 7 + tg];
        sc += mi ? (ttag + etag) : 0.0f;
        mc += mi ? 1 : 0;
        tp = tg;
        float a[7] = {0.f,0.f,0.f,0.f,0.f,0.f,0.f};
#pragma unroll
        for (int r = 0; r < 7; ++r) {
          float vr = v[r];
#pragma unroll
          for (int t = 0; t < 7; ++t) a[t] = fmaf(vr, Es[r*7+t], a[t]);
        }
#pragma unroll
        for (int t = 0; t < 7; ++t) v[t] = mi ? a[t] * ee[t] : v[t];
      };

      float eA0[7], eA1[7], eB0[7], eB1[7];
      int tgA0, miA0, tgA1, miA1, tgB0, miB0, tgB1, miB1;
      LDfA(0, eA0, tgA0, miA0);
      LDfB(0, eB0, tgB0, miB0);

      for (int h = 0; h < CC / 2; ++h) {
        int j0 = 2 * h;
        LDfA(j0 + 1, eA1, tgA1, miA1);          // Y loads
        LDfB(j0 + 1, eB1, tgB1, miB1);
        int mA = (c1 == 0 && j0 == 0) ? 0 : miA0;   // boundary step
        FSTEP(eA0, tgA0, mA,   vA, scA, mcA, tpA);
        FSTEP(eB0, tgB0, miB0, vB, scB, mcB, tpB);
        int jn = (j0 + 2 < CC) ? j0 + 2 : CC - 1;   // clamp: harmless reload
        LDfA(jn, eA0, tgA0, miA0);              // X loads (next pair)
        LDfB(jn, eB0, tgB0, miB0);
        FSTEP(eA1, tgA1, miA1, vA, scA, mcA, tpA);
        FSTEP(eB1, tgB1, miB1, vB, scB, mcB, tpB);
        if ((h & 3) == 3) {                     // renorm after steps 7,15,23,31
          float sA = vA[0]+vA[1]+vA[2]+vA[3]+vA[4]+vA[5]+vA[6];
          float sB = vB[0]+vB[1]+vB[2]+vB[3]+vB[4]+vB[5]+vB[6];
          LvA += logf(sA); LvB += logf(sB);
          float i2A = 1.0f / sA, i2B = 1.0f / sB;
#pragma unroll
          for (int t = 0; t < 7; ++t) { vA[t] *= i2A; vB[t] *= i2B; }
        }
      }
    } else {
      // ---- slow path: R15 loop verbatim (handles cont flips) ----
      auto LDA = [&](int s, float* e, int& tg, int& qm, int& mi) {
        size_t base = (size_t)(iA + s) * BB + b;
        ld7(em + base * TT, e);
        tg = tags[base]; qm = qmask[base]; mi = mask[base];
      };
      auto LDB = [&](int s, float* e, int& tg, int& qm, int& mi) {
        size_t base = (size_t)(iB + s) * BB + b;
        ld7(em + base * TT, e);
        tg = tags[base]; qm = qmask[base]; mi = mask[base];
      };
      auto STEP = [&](const float* e, int tg, int qm, int mi,
                      float* v, float& sc, int& mc, int& tp, int& qp) {
        int cont = (qm != qp) ? 1 : 0;
        int cf = __builtin_amdgcn_readfirstlane(cont);
        bool uni = __all(cont == cf);
        float ee[7];
#pragma unroll
        for (int t = 0; t < 7; ++t) ee[t] = __expf(e[t]);
        float etag = e[0];
#pragma unroll
        for (int t = 1; t < 7; ++t) etag = (tg == t) ? e[t] : etag;
        float ttag = sT[cont][tp * 7 + tg];
        if (mi) { sc += ttag + etag; ++mc; }
        tp = tg; qp = qm;
        float a[7] = {0.f,0.f,0.f,0.f,0.f,0.f,0.f};
        if (uni) {
          if (cf != loadedCont) loadEs(cf);
#pragma unroll
          for (int r = 0; r < 7; ++r) {
            float vr = v[r];
#pragma unroll
            for (int t = 0; t < 7; ++t) a[t] = fmaf(vr, Es[r*7+t], a[t]);
          }
        } else {
          loadedCont = -1;
#pragma unroll
          for (int r = 0; r < 7; ++r) {
            float vr = v[r];
#pragma unroll
            for (int t = 0; t < 7; ++t) a[t] = fmaf(vr, sE[cont][r*7+t], a[t]);
          }
        }
#pragma unroll
        for (int t = 0; t < 7; ++t) v[t] = mi ? a[t] * ee[t] : v[t];
      };

      float eA0[7], eA1[7], eB0[7], eB1[7];
      int tgA0, qmA0, miA0, tgA1, qmA1, miA1;
      int tgB0, qmB0, miB0, tgB1, qmB1, miB1;
      LDA(0, eA0, tgA0, qmA0, miA0);
      LDB(0, eB0, tgB0, qmB0, miB0);
      for (int j = 0; j < CC; ++j) {
        bool more = (j + 1 < CC);
        if (more) {
          LDA(j + 1, eA1, tgA1, qmA1, miA1);
          LDB(j + 1, eB1, tgB1, qmB1, miB1);
        }
        int miA = (c1 == 0 && j == 0) ? 0 : miA0;
        STEP(eA0, tgA0, qmA0, miA, vA, scA, mcA, tpA, qpA);
        STEP(eB0, tgB0, qmB0, miB0, vB, scB, mcB, tpB, qpB);
        if ((j & 7) == 7) {
          float sA = vA[0]+vA[1]+vA[2]+vA[3]+vA[4]+vA[5]+vA[6];
          float sB = vB[0]+vB[1]+vB[2]+vB[3]+vB[4]+vB[5]+vB[6];
          LvA += logf(sA); LvB += logf(sB);
          float i2A = 1.0f / sA, i2B = 1.0f / sB;
#pragma unroll
          for (int t = 0; t < 7; ++t) { vA[t] *= i2A; vB[t] *= i2B; }
        }
        if (more) {
#pragma unroll
          for (int t = 0; t < 7; ++t) { eA0[t] = eA1[t]; eB0[t] = eB1[t]; }
          tgA0 = tgA1; qmA0 = qmA1; miA0 = miA1;
          tgB0 = tgB1; qmB0 = qmB1; miB0 = miB1;
        }
      }
    }

    float sA = vA[0]+vA[1]+vA[2]+vA[3]+vA[4]+vA[5]+vA[6];
    float sB = vB[0]+vB[1]+vB[2]+vB[3]+vB[4]+vB[5]+vB[6];
    float i2A = 1.0f / sA, i2B = 1.0f / sB;
#pragma unroll
    for (int t = 0; t < 7; ++t) {
      recs[(size_t)t * NG + g1] = vA[t] * i2A;
      recs[(size_t)t * NG + g2] = vB[t] * i2B;
    }
    recs[(size_t)14 * NG + g1] = scA;
    recs[(size_t)14 * NG + g2] = scB;
    recs[(size_t)15 * NG + g1] = (float)mcA;
    recs[(size_t)15 * NG + g2] = (float)mcB;
    recs[(size_t)16 * NG + g1] = LvA + logf(sA);   // Lmass = log(1^T P 1)
    recs[(size_t)16 * NG + g2] = LvB + logf(sB);
  } else {
    // ============ backward: u direction, NB steps (2 streams) =============
    float rA[7], rB[7];
#pragma unroll
    for (int t = 0; t < 7; ++t) { rA[t] = 1.f; rB[t] = 1.f; }
    int iloA = (c1 == 0) ? 1 : c1 * CC;
    int iloB = c2 * CC;

    // ---- prescan ----
    int afA = 0, afB = 0;
    {
      int prevA = qmask[(size_t)(iloA - 1) * BB + b];
      int prevB = qmask[(size_t)(iloB - 1) * BB + b];
#pragma unroll
      for (int s = 0; s < NB; ++s) {
        int qa = qmask[(size_t)(iloA + s) * BB + b];
        int qb = qmask[(size_t)(iloB + s) * BB + b];
        afA |= (qa != prevA); prevA = qa;
        afB |= (qb != prevB); prevB = qb;
      }
    }
    bool fast = !__any(afA | afB);

    auto LDeA = [&](int s, float* e, int& mi) {
      size_t base = (size_t)(iloA + NB - 1 - s) * BB + b;
      ld7(em + base * TT, e);
      mi = mask[base];
    };
    auto LDeB = [&](int s, float* e, int& mi) {
      size_t base = (size_t)(iloB + NB - 1 - s) * BB + b;
      ld7(em + base * TT, e);
      mi = mask[base];
    };

    if (fast) {
      loadEs(0);
      auto BSTEP = [&](const float* e, int mi, float* r) {
        float ee[7];
#pragma unroll
        for (int t = 0; t < 7; ++t) ee[t] = __expf(e[t]);
        float tmp[7];
#pragma unroll
        for (int t = 0; t < 7; ++t) tmp[t] = ee[t] * r[t];
        float a[7] = {0.f,0.f,0.f,0.f,0.f,0.f,0.f};
#pragma unroll
        for (int t = 0; t < 7; ++t) {
          float tt = tmp[t];
#pragma unroll
          for (int s2 = 0; s2 < 7; ++s2) a[s2] = fmaf(tt, Es[s2*7+t], a[s2]);
        }
#pragma unroll
        for (int s2 = 0; s2 < 7; ++s2) r[s2] = mi ? a[s2] : r[s2];
      };

      float eA0[7], eA1[7], eB0[7], eB1[7];
      int miA0, miA1, miB0, miB1;
      LDeA(0, eA0, miA0);
      LDeB(0, eB0, miB0);
      for (int h = 0; h < NB / 2; ++h) {
        int j0 = 2 * h;
        LDeA(j0 + 1, eA1, miA1);
        LDeB(j0 + 1, eB1, miB1);
        BSTEP(eA0, miA0, rA);
        BSTEP(eB0, miB0, rB);
        int jn = (j0 + 2 < NB) ? j0 + 2 : NB - 1;
        LDeA(jn, eA0, miA0);
        LDeB(jn, eB0, miB0);
        BSTEP(eA1, miA1, rA);
        BSTEP(eB1, miB1, rB);
        if (h == 2) {                            // overflow guard (step 5)
          float sA = rA[0]+rA[1]+rA[2]+rA[3]+rA[4]+rA[5]+rA[6];
          float sB = rB[0]+rB[1]+rB[2]+rB[3]+rB[4]+rB[5]+rB[6];
          float i2A = 1.0f / sA, i2B = 1.0f / sB;
#pragma unroll
          for (int t = 0; t < 7; ++t) { rA[t] *= i2A; rB[t] *= i2B; }
        }
      }
    } else {
      // ---- slow path: R15 backward loop verbatim ----
      auto LDbA = [&](int s, float* e, int& q, int& q1, int& mi2) {
        size_t base = (size_t)(iloA + NB - 1 - s) * BB + b;
        ld7(em + base * TT, e);
        q = qmask[base]; q1 = qmask[base - BB]; mi2 = mask[base];
      };
      auto LDbB = [&](int s, float* e, int& q, int& q1, int& mi2) {
        size_t base = (size_t)(iloB + NB - 1 - s) * BB + b;
        ld7(em + base * TT, e);
        q = qmask[base]; q1 = qmask[base - BB]; mi2 = mask[base];
      };
      auto STEPB = [&](const float* e, int q, int q1, int mi2, float* r) {
        int cont = (q != q1) ? 1 : 0;
        int cf = __builtin_amdgcn_readfirstlane(cont);
        bool uni = __all(cont == cf);
        float ee[7];
#pragma unroll
        for (int t = 0; t < 7; ++t) ee[t] = __expf(e[t]);
        float tmp[7];
#pragma unroll
        for (int t = 0; t < 7; ++t) tmp[t] = ee[t] * r[t];
        float a[7] = {0.f,0.f,0.f,0.f,0.f,0.f,0.f};
        if (uni) {
          if (cf != loadedCont) loadEs(cf);
#pragma unroll
          for (int t = 0; t < 7; ++t) {
            float tt = tmp[t];
#pragma unroll
            for (int s2 = 0; s2 < 7; ++s2) a[s2] = fmaf(tt, Es[s2*7+t], a[s2]);
          }
        } else {
          loadedCont = -1;
#pragma unroll
          for (int t = 0; t < 7; ++t) {
            float tt = tmp[t];
#pragma unroll
            for (int s2 = 0; s2 < 7; ++s2) a[s2] = fmaf(tt, sE[cont][s2*7+t], a[s2]);
          }
        }
#pragma unroll
        for (int s2 = 0; s2 < 7; ++s2) r[s2] = mi2 ? a[s2] : r[s2];
      };

      float eA0[7], eA1[7], eB0[7], eB1[7];
      int qA0, q1A0, mA0, qA1, q1A1, mA1;
      int qB0, q1B0, mB0, qB1, q1B1, mB1;
      LDbA(0, eA0, qA0, q1A0, mA0);
      LDbB(0, eB0, qB0, q1B0, mB0);
      for (int j = 0; j < NB; ++j) {
        bool more = (j + 1 < NB);
        if (more) {
          LDbA(j + 1, eA1, qA1, q1A1, mA1);
          LDbB(j + 1, eB1, qB1, q1B1, mB1);
        }
        STEPB(eA0, qA0, q1A0, mA0, rA);
        STEPB(eB0, qB0, q1B0, mB0, rB);
        if (j == 5) {
          float sA = rA[0]+rA[1]+rA[2]+rA[3]+rA[4]+rA[5]+rA[6];
          float sB = rB[0]+rB[1]+rB[2]+rB[3]+rB[4]+rB[5]+rB[6];
          float i2A = 1.0f / sA, i2B = 1.0f / sB;
#pragma unroll
          for (int t = 0; t < 7; ++t) { rA[t] *= i2A; rB[t] *= i2B; }
        }
        if (more) {
#pragma unroll
          for (int t = 0; t < 7; ++t) { eA0[t] = eA1[t]; eB0[t] = eB1[t]; }
          qA0 = qA1; q1A0 = q1A1; mA0 = mA1;
          qB0 = qB1; q1B0 = q1B1; mB0 = mB1;
        }
      }
    }

    float sA = rA[0]+rA[1]+rA[2]+rA[3]+rA[4]+rA[5]+rA[6];
    float sB = rB[0]+rB[1]+rB[2]+rB[3]+rB[4]+rB[5]+rB[6];
    float i2A = 1.0f / sA, i2B = 1.0f / sB;
#pragma unroll
    for (int t = 0; t < 7; ++t) {
      recs[(size_t)(7 + t) * NG + g1] = rA[t] * i2A;
      recs[(size_t)(7 + t) * NG + g2] = rB[t] * i2B;
    }
  }
}

// ---------------------------------------------------------------------------
// Kernel 2: flat-parallel junction terms + per-block tree reduction.
// ---------------------------------------------------------------------------
template<int KCH>
__global__ __launch_bounds__(256)
void crf_junction_kernel(const float* __restrict__ recs,
                         const float* __restrict__ em,
                         const int*   __restrict__ tags,
                         const float* __restrict__ start_t,
                         const float* __restrict__ end_t,
                         float* __restrict__ partials) {
  constexpr int NG = KCH * BB;
  int tid = threadIdx.x;
  int g = blockIdx.x * 256 + tid;
  int b = g & (BB - 1);
  int c = g >> 11;
  float rn[7];
#pragma unroll
  for (int t = 0; t < 7; ++t) rn[t] = recs[(size_t)(7 + t) * NG + g];
  float term = recs[(size_t)14 * NG + g] - recs[(size_t)16 * NG + g];
  float dot = 0.f;
  if (c == 0) {
    float e0[7], st[7];
#pragma unroll
    for (int t = 0; t < 7; ++t) { e0[t] = em[(size_t)b * TT + t]; st[t] = start_t[t]; }
#pragma unroll
    for (int t = 0; t < 7; ++t) dot = fmaf(__expf(st[t] + e0[t]), rn[t], dot);
    int tg0 = tags[b];
    float em0t = e0[0], stt = st[0];
#pragma unroll
    for (int t = 1; t < 7; ++t) {
      em0t = (tg0 == t) ? e0[t] : em0t;
      stt  = (tg0 == t) ? st[t] : stt;
    }
    term += stt + em0t;
  } else {
#pragma unroll
    for (int t = 0; t < 7; ++t)
      dot = fmaf(recs[(size_t)t * NG + (g - BB)], rn[t], dot);
  }
  term -= logf(dot);
  if (c == KCH - 1) {
    float fz = 0.f;
#pragma unroll
    for (int t = 0; t < 7; ++t)
      fz = fmaf(recs[(size_t)t * NG + g], __expf(end_t[t]), fz);
    term -= logf(fz);
    float mcf = 0.f;
    for (int cc = 0; cc < KCH; ++cc)
      mcf += recs[(size_t)15 * NG + (size_t)cc * BB + b];
    int se = (int)mcf - 1;
    int te = tags[(size_t)se * BB + b];
    term += end_t[te];
  }
  __shared__ float red[256];
  red[tid] = term;
  __syncthreads();
  for (int off = 128; off > 0; off >>= 1) {
    if (tid < off) red[tid] += red[tid + off];
    __syncthreads();
  }
  if (tid == 0) partials[blockIdx.x] = red[0];
}

// ---------------------------------------------------------------------------
// Kernel 3: deterministic tree-reduce of the block partials.
// ---------------------------------------------------------------------------
__global__ __launch_bounds__(1024)
void crf_reduce_kernel(const float* __restrict__ partials, int n,
                       float* __restrict__ out) {
  __shared__ float s[1024];
  int t = threadIdx.x;
  float v = 0.f;
  for (int i = t; i < n; i += 1024) v += partials[i];
  s[t] = v;
  __syncthreads();
  for (int off = 512; off > 0; off >>= 1) {
    if (t < off) s[t] += s[t + off];
    __syncthreads();
  }
  if (t == 0) out[0] = s[0];
}

extern "C" void kernel_launch(void* const* d_in, const int* in_sizes, int n_in,
                              void* d_out, int out_size, void* d_ws, size_t ws_size,
                              hipStream_t stream) {
  const float* em      = (const float*)d_in[0];
  const int*   tags    = (const int*)d_in[1];
  const int*   qmask   = (const int*)d_in[2];
  const int*   mask    = (const int*)d_in[3];
  const float* start_t = (const float*)d_in[4];
  const float* end_t   = (const float*)d_in[5];
  const float* self_t  = (const float*)d_in[6];
  const float* other_t = (const float*)d_in[7];

  float* recs = (float*)d_ws;

  constexpr int KCH = 64;     // CC=32; ws need ~8.9 MB
  constexpr int NG  = KCH * BB;
  float* partials = recs + (size_t)NFLD * NG;

  crf_chunk_kernel<KCH><<<(NG / 2) / 128, 256, 0, stream>>>(
      em, tags, qmask, mask, self_t, other_t, recs);
  crf_junction_kernel<KCH><<<NG / 256, 256, 0, stream>>>(
      recs, em, tags, start_t, end_t, partials);
  crf_reduce_kernel<<<1, 1024, 0, stream>>>(partials, NG / 256, (float*)d_out);
}

// Round 20
// 51.934 us; speedup vs baseline: 1.3884x; 1.0659x over previous
//
#include <hip/hip_runtime.h>
#include <hip/hip_bf16.h>

#define LSEQ 2048
#define BB   2048
#define TT   7
#define NFLD 17   // SoA fields: [0..6] vn, [7..13] rn, [14] sc, [15] mc, [16] Lmass

typedef float f4 __attribute__((ext_vector_type(4)));

// Load 7 floats from a 4B-aligned row as two overlapping dwordx4 loads.
__device__ __forceinline__ void ld7(const float* __restrict__ p, float* e) {
  f4 lo, hi;
  __builtin_memcpy(&lo, p, 16);
  __builtin_memcpy(&hi, p + 3, 16);
  e[0] = lo.x; e[1] = lo.y; e[2] = lo.z; e[3] = lo.w;
  e[4] = hi.y; e[5] = hi.z; e[6] = hi.w;
}

// ---------------------------------------------------------------------------
// Rank-1 chunk decomposition, v8 = R15 champion verbatim with NB=12 -> 8.
// P_c = u s v^T, s = 1^T P 1.
//   forward (CC=32 steps): v <- (v.E) o ee -> vn, Lmass, gold sc, mask count.
//   backward (NB=8 steps): u DIRECTION only; Hilbert contraction ~0.1/step
//     -> 1e-8 accuracy (threshold is 2e5; summed error ~0.02).
// DUAL-STREAM: each thread runs TWO independent chunks (c, c+KCH/2).
// Falsified theories (do not retry): occupancy scaling (R16), L1
// line-transaction wall (R18: coalesced LDS tiles slower), convergent-op
// scheduling barrier (R19: branch-free loop no faster). The recurrence is
// bound by sequential per-step memory round-trips; R15's dual-stream form
// is the empirical optimum of that structure.
// NOTE: no asm-load rings (R14 fault); no min-wave launch_bounds (R5/R7).
// ---------------------------------------------------------------------------
template<int KCH>
__global__ __launch_bounds__(256)
void crf_chunk_kernel(const float* __restrict__ em,
                      const int*   __restrict__ tags,
                      const int*   __restrict__ qmask,
                      const int*   __restrict__ mask,
                      const float* __restrict__ self_t,
                      const float* __restrict__ other_t,
                      float* __restrict__ recs) {
  constexpr int CC  = LSEQ / KCH;   // 32
  constexpr int NG  = KCH * BB;
  constexpr int NGH = NG / 2;
  constexpr int NB  = 8;            // backward steps for the u direction
  __shared__ float sE[2][49];       // exp(transitions): [0]=self, [1]=other
  __shared__ float sT[2][49];       // raw transitions (gold-path score)
  int tid = threadIdx.x;
  if (tid < 49) {
    float sv = self_t[tid], ov = other_t[tid];
    sE[0][tid] = __expf(sv); sE[1][tid] = __expf(ov);
    sT[0][tid] = sv;         sT[1][tid] = ov;
  }
  __syncthreads();

  int role = tid >> 7;              // wave-uniform: 0 = forward, 1 = backward
  int p = blockIdx.x * 128 + (tid & 127);   // pair id
  int b  = p & (BB - 1);
  int c1 = p >> 11;                 // uniform per block (128 | 2048)
  int c2 = c1 + KCH / 2;
  int g1 = p, g2 = p + NGH;

  float Es[49];                     // SGPR-resident via readfirstlane when uniform
  int loadedCont = -1;
  auto loadEs = [&](int cf) {
#pragma unroll
    for (int k = 0; k < 49; ++k)
      Es[k] = __int_as_float(
          __builtin_amdgcn_readfirstlane(__float_as_int(sE[cf][k])));
    loadedCont = cf;
  };

  if (role == 0) {
    // ---------------- forward: vn, Lmass, gold score (2 streams) ----------
    float vA[7], vB[7];
#pragma unroll
    for (int t = 0; t < 7; ++t) { vA[t] = 1.f; vB[t] = 1.f; }
    float scA = 0.f, scB = 0.f, LvA = 0.f, LvB = 0.f;
    int mcA = 0, mcB = 0, tpA, qpA, tpB, qpB;
    int iA = c1 * CC, iB = c2 * CC;
    if (c1 == 0) { mcA = mask[b]; tpA = tags[b]; qpA = qmask[b]; }
    else { size_t pb = (size_t)(iA - 1) * BB + b; tpA = tags[pb]; qpA = qmask[pb]; }
    { size_t pb = (size_t)(iB - 1) * BB + b; tpB = tags[pb]; qpB = qmask[pb]; }

    auto LDA = [&](int s, float* e, int& tg, int& qm, int& mi) {
      size_t base = (size_t)(iA + s) * BB + b;
      ld7(em + base * TT, e);
      tg = tags[base]; qm = qmask[base]; mi = mask[base];
    };
    auto LDB = [&](int s, float* e, int& tg, int& qm, int& mi) {
      size_t base = (size_t)(iB + s) * BB + b;
      ld7(em + base * TT, e);
      tg = tags[base]; qm = qmask[base]; mi = mask[base];
    };

    auto STEP = [&](const float* e, int tg, int qm, int mi,
                    float* v, float& sc, int& mc, int& tp, int& qp) {
      int cont = (qm != qp) ? 1 : 0;
      int cf = __builtin_amdgcn_readfirstlane(cont);
      bool uni = __all(cont == cf);
      float ee[7];
#pragma unroll
      for (int t = 0; t < 7; ++t) ee[t] = __expf(e[t]);
      float etag = e[0];
#pragma unroll
      for (int t = 1; t < 7; ++t) etag = (tg == t) ? e[t] : etag;
      float ttag = sT[cont][tp * 7 + tg];
      if (mi) { sc += ttag + etag; ++mc; }
      tp = tg; qp = qm;
      float a[7] = {0.f,0.f,0.f,0.f,0.f,0.f,0.f};
      if (uni) {
        if (cf != loadedCont) loadEs(cf);
#pragma unroll
        for (int r = 0; r < 7; ++r) {
          float vr = v[r];
#pragma unroll
          for (int t = 0; t < 7; ++t) a[t] = fmaf(vr, Es[r*7+t], a[t]);
        }
      } else {
        loadedCont = -1;
#pragma unroll
        for (int r = 0; r < 7; ++r) {
          float vr = v[r];
#pragma unroll
          for (int t = 0; t < 7; ++t) a[t] = fmaf(vr, sE[cont][r*7+t], a[t]);
        }
      }
#pragma unroll
      for (int t = 0; t < 7; ++t) v[t] = mi ? a[t] * ee[t] : v[t];
    };

    float eA0[7], eA1[7], eB0[7], eB1[7];
    int tgA0, qmA0, miA0, tgA1, qmA1, miA1;
    int tgB0, qmB0, miB0, tgB1, qmB1, miB1;
    LDA(0, eA0, tgA0, qmA0, miA0);
    LDB(0, eB0, tgB0, qmB0, miB0);

    for (int j = 0; j < CC; ++j) {
      bool more = (j + 1 < CC);                     // wave-uniform
      if (more) {
        LDA(j + 1, eA1, tgA1, qmA1, miA1);          // issue next-step loads
        LDB(j + 1, eB1, tgB1, qmB1, miB1);
      }
      int miA = (c1 == 0 && j == 0) ? 0 : miA0;     // boundary step = identity
      STEP(eA0, tgA0, qmA0, miA, vA, scA, mcA, tpA, qpA);
      STEP(eB0, tgB0, qmB0, miB0, vB, scB, mcB, tpB, qpB);
      if ((j & 7) == 7) {                           // renorm, track log mass
        float sA = vA[0]+vA[1]+vA[2]+vA[3]+vA[4]+vA[5]+vA[6];
        float sB = vB[0]+vB[1]+vB[2]+vB[3]+vB[4]+vB[5]+vB[6];
        LvA += logf(sA); LvB += logf(sB);
        float iA2 = 1.0f / sA, iB2 = 1.0f / sB;
#pragma unroll
        for (int t = 0; t < 7; ++t) { vA[t] *= iA2; vB[t] *= iB2; }
      }
      if (more) {
#pragma unroll
        for (int t = 0; t < 7; ++t) { eA0[t] = eA1[t]; eB0[t] = eB1[t]; }
        tgA0 = tgA1; qmA0 = qmA1; miA0 = miA1;
        tgB0 = tgB1; qmB0 = qmB1; miB0 = miB1;
      }
    }
    float sA = vA[0]+vA[1]+vA[2]+vA[3]+vA[4]+vA[5]+vA[6];
    float sB = vB[0]+vB[1]+vB[2]+vB[3]+vB[4]+vB[5]+vB[6];
    float iA2 = 1.0f / sA, iB2 = 1.0f / sB;
#pragma unroll
    for (int t = 0; t < 7; ++t) {
      recs[(size_t)t * NG + g1] = vA[t] * iA2;
      recs[(size_t)t * NG + g2] = vB[t] * iB2;
    }
    recs[(size_t)14 * NG + g1] = scA;
    recs[(size_t)14 * NG + g2] = scB;
    recs[(size_t)15 * NG + g1] = (float)mcA;
    recs[(size_t)15 * NG + g2] = (float)mcB;
    recs[(size_t)16 * NG + g1] = LvA + logf(sA);    // Lmass = log(1^T P 1)
    recs[(size_t)16 * NG + g2] = LvB + logf(sB);
  } else {
    // ---------------- backward: u direction, NB steps (2 streams) ---------
    float rA[7], rB[7];
#pragma unroll
    for (int t = 0; t < 7; ++t) { rA[t] = 1.f; rB[t] = 1.f; }
    int iloA = (c1 == 0) ? 1 : c1 * CC;
    int iloB = c2 * CC;

    auto LDbA = [&](int s, float* e, int& q, int& q1, int& mi2) {
      size_t base = (size_t)(iloA + NB - 1 - s) * BB + b;   // i >= 1
      ld7(em + base * TT, e);
      q = qmask[base]; q1 = qmask[base - BB]; mi2 = mask[base];
    };
    auto LDbB = [&](int s, float* e, int& q, int& q1, int& mi2) {
      size_t base = (size_t)(iloB + NB - 1 - s) * BB + b;
      ld7(em + base * TT, e);
      q = qmask[base]; q1 = qmask[base - BB]; mi2 = mask[base];
    };

    auto STEPB = [&](const float* e, int q, int q1, int mi2, float* r) {
      int cont = (q != q1) ? 1 : 0;
      int cf = __builtin_amdgcn_readfirstlane(cont);
      bool uni = __all(cont == cf);
      float ee[7];
#pragma unroll
      for (int t = 0; t < 7; ++t) ee[t] = __expf(e[t]);
      float tmp[7];
#pragma unroll
      for (int t = 0; t < 7; ++t) tmp[t] = ee[t] * r[t];
      float a[7] = {0.f,0.f,0.f,0.f,0.f,0.f,0.f};
      if (uni) {
        if (cf != loadedCont) loadEs(cf);
#pragma unroll
        for (int t = 0; t < 7; ++t) {
          float tt = tmp[t];
#pragma unroll
          for (int s2 = 0; s2 < 7; ++s2) a[s2] = fmaf(tt, Es[s2*7+t], a[s2]);
        }
      } else {
        loadedCont = -1;
#pragma unroll
        for (int t = 0; t < 7; ++t) {
          float tt = tmp[t];
#pragma unroll
          for (int s2 = 0; s2 < 7; ++s2) a[s2] = fmaf(tt, sE[cont][s2*7+t], a[s2]);
        }
      }
#pragma unroll
      for (int s2 = 0; s2 < 7; ++s2) r[s2] = mi2 ? a[s2] : r[s2];
    };

    float eA0[7], eA1[7], eB0[7], eB1[7];
    int qA0, q1A0, mA0, qA1, q1A1, mA1;
    int qB0, q1B0, mB0, qB1, q1B1, mB1;
    LDbA(0, eA0, qA0, q1A0, mA0);
    LDbB(0, eB0, qB0, q1B0, mB0);

    for (int j = 0; j < NB; ++j) {
      bool more = (j + 1 < NB);
      if (more) {
        LDbA(j + 1, eA1, qA1, q1A1, mA1);
        LDbB(j + 1, eB1, qB1, q1B1, mB1);
      }
      STEPB(eA0, qA0, q1A0, mA0, rA);
      STEPB(eB0, qB0, q1B0, mB0, rB);
      if (j == 3) {                                 // overflow guard (mid-pass)
        float sA = rA[0]+rA[1]+rA[2]+rA[3]+rA[4]+rA[5]+rA[6];
        float sB = rB[0]+rB[1]+rB[2]+rB[3]+rB[4]+rB[5]+rB[6];
        float iA2 = 1.0f / sA, iB2 = 1.0f / sB;
#pragma unroll
        for (int t = 0; t < 7; ++t) { rA[t] *= iA2; rB[t] *= iB2; }
      }
      if (more) {
#pragma unroll
        for (int t = 0; t < 7; ++t) { eA0[t] = eA1[t]; eB0[t] = eB1[t]; }
        qA0 = qA1; q1A0 = q1A1; mA0 = mA1;
        qB0 = qB1; q1B0 = q1B1; mB0 = mB1;
      }
    }
    float sA = rA[0]+rA[1]+rA[2]+rA[3]+rA[4]+rA[5]+rA[6];
    float sB = rB[0]+rB[1]+rB[2]+rB[3]+rB[4]+rB[5]+rB[6];
    float iA2 = 1.0f / sA, iB2 = 1.0f / sB;
#pragma unroll
    for (int t = 0; t < 7; ++t) {
      recs[(size_t)(7 + t) * NG + g1] = rA[t] * iA2;
      recs[(size_t)(7 + t) * NG + g2] = rB[t] * iB2;
    }
  }
}

// ---------------------------------------------------------------------------
// Kernel 2: flat-parallel junction terms + per-block tree reduction.
// term(b,c) = sc - Lmass - log(dot); dot_0 = alpha0.rn_0 (+gold start terms),
// dot_c = vn_{c-1}.rn_c; c==KCH-1 folds the final logZ term and gold end.
// ---------------------------------------------------------------------------
template<int KCH>
__global__ __launch_bounds__(256)
void crf_junction_kernel(const float* __restrict__ recs,
                         const float* __restrict__ em,
                         const int*   __restrict__ tags,
                         const float* __restrict__ start_t,
                         const float* __restrict__ end_t,
                         float* __restrict__ partials) {
  constexpr int NG = KCH * BB;
  int tid = threadIdx.x;
  int g = blockIdx.x * 256 + tid;
  int b = g & (BB - 1);
  int c = g >> 11;                       // block-uniform (256 | 2048)
  float rn[7];
#pragma unroll
  for (int t = 0; t < 7; ++t) rn[t] = recs[(size_t)(7 + t) * NG + g];
  float term = recs[(size_t)14 * NG + g] - recs[(size_t)16 * NG + g];
  float dot = 0.f;
  if (c == 0) {
    float e0[7], st[7];
#pragma unroll
    for (int t = 0; t < 7; ++t) { e0[t] = em[(size_t)b * TT + t]; st[t] = start_t[t]; }
#pragma unroll
    for (int t = 0; t < 7; ++t) dot = fmaf(__expf(st[t] + e0[t]), rn[t], dot);
    int tg0 = tags[b];
    float em0t = e0[0], stt = st[0];
#pragma unroll
    for (int t = 1; t < 7; ++t) {
      em0t = (tg0 == t) ? e0[t] : em0t;
      stt  = (tg0 == t) ? st[t] : stt;
    }
    term += stt + em0t;                  // gold start + em[0][tag0]
  } else {
#pragma unroll
    for (int t = 0; t < 7; ++t)
      dot = fmaf(recs[(size_t)t * NG + (g - BB)], rn[t], dot);
  }
  term -= logf(dot);
  if (c == KCH - 1) {
    float fz = 0.f;
#pragma unroll
    for (int t = 0; t < 7; ++t)
      fz = fmaf(recs[(size_t)t * NG + g], __expf(end_t[t]), fz);
    term -= logf(fz);                    // final logZ term (own vn)
    float mcf = 0.f;
    for (int cc = 0; cc < KCH; ++cc)
      mcf += recs[(size_t)15 * NG + (size_t)cc * BB + b];
    int se = (int)mcf - 1;
    int te = tags[(size_t)se * BB + b];
    term += end_t[te];                   // gold end transition
  }
  __shared__ float red[256];
  red[tid] = term;
  __syncthreads();
  for (int off = 128; off > 0; off >>= 1) {
    if (tid < off) red[tid] += red[tid + off];
    __syncthreads();
  }
  if (tid == 0) partials[blockIdx.x] = red[0];
}

// ---------------------------------------------------------------------------
// Kernel 3: deterministic tree-reduce of the block partials.
// ---------------------------------------------------------------------------
__global__ __launch_bounds__(1024)
void crf_reduce_kernel(const float* __restrict__ partials, int n,
                       float* __restrict__ out) {
  __shared__ float s[1024];
  int t = threadIdx.x;
  float v = 0.f;
  for (int i = t; i < n; i += 1024) v += partials[i];
  s[t] = v;
  __syncthreads();
  for (int off = 512; off > 0; off >>= 1) {
    if (t < off) s[t] += s[t + off];
    __syncthreads();
  }
  if (t == 0) out[0] = s[0];
}

extern "C" void kernel_launch(void* const* d_in, const int* in_sizes, int n_in,
                              void* d_out, int out_size, void* d_ws, size_t ws_size,
                              hipStream_t stream) {
  const float* em      = (const float*)d_in[0];
  const int*   tags    = (const int*)d_in[1];
  const int*   qmask   = (const int*)d_in[2];
  const int*   mask    = (const int*)d_in[3];
  const float* start_t = (const float*)d_in[4];
  const float* end_t   = (const float*)d_in[5];
  const float* self_t  = (const float*)d_in[6];
  const float* other_t = (const float*)d_in[7];

  float* recs = (float*)d_ws;

  constexpr int KCH = 64;     // CC=32; ws need ~8.9 MB
  constexpr int NG  = KCH * BB;
  float* partials = recs + (size_t)NFLD * NG;

  crf_chunk_kernel<KCH><<<(NG / 2) / 128, 256, 0, stream>>>(
      em, tags, qmask, mask, self_t, other_t, recs);
  crf_junction_kernel<KCH><<<NG / 256, 256, 0, stream>>>(
      recs, em, tags, start_t, end_t, partials);
  crf_reduce_kernel<<<1, 1024, 0, stream>>>(partials, NG / 256, (float*)d_out);
}

// Round 21
// 44.039 us; speedup vs baseline: 1.6372x; 1.1793x over previous
//
#include <hip/hip_runtime.h>
#include <hip/hip_bf16.h>

#define LSEQ 2048
#define BB   2048
#define TT   7
#define NFLD 17   // SoA fields: [0..6] vn, [7..13] rn, [14] sc, [15] mc, [16] Lmass

typedef float f4 __attribute__((ext_vector_type(4)));

// Load 7 floats from a 4B-aligned row as two overlapping dwordx4 loads.
__device__ __forceinline__ void ld7(const float* __restrict__ p, float* e) {
  f4 lo, hi;
  __builtin_memcpy(&lo, p, 16);
  __builtin_memcpy(&hi, p + 3, 16);
  e[0] = lo.x; e[1] = lo.y; e[2] = lo.z; e[3] = lo.w;
  e[4] = hi.y; e[5] = hi.z; e[6] = hi.w;
}

// ---------------------------------------------------------------------------
// Rank-1 chunk decomposition, v9. P_c = u s v^T, s = 1^T P 1.
//   forward (CC=32 steps, 1 chunk/thread): v <- (v.E) o ee -> vn, Lmass,
//     gold sc, mask count.
//   backward (NB=8 steps, 1 chunk/thread): u DIRECTION only (~1e-8).
// MODEL (fits R12/R16/R20 exactly): time = bytes / BW(total_waves), BW
// saturates ~2.1 TB/s at >=3000 waves (MLP-limited; stream count per thread
// irrelevant). R20 had minimum bytes (~100MB) but only 1536 waves (1.39
// TB/s). This round: S=1 both roles -> 2048 fwd + 1024 bwd = 3072 waves at
// the same byte budget.
// Falsified (do not retry): occupancy-via-bigger-KCH (adds bytes, R16), LDS
// em tiles (R11/R18), branch-free/convergent-free loops (R19), asm rings
// (R14 fault), min-wave launch_bounds (R5/R7 spill).
// ---------------------------------------------------------------------------
template<int KCH>
__global__ __launch_bounds__(256)
void crf_chunk_kernel(const float* __restrict__ em,
                      const int*   __restrict__ tags,
                      const int*   __restrict__ qmask,
                      const int*   __restrict__ mask,
                      const float* __restrict__ self_t,
                      const float* __restrict__ other_t,
                      float* __restrict__ recs) {
  constexpr int CC   = LSEQ / KCH;   // 32
  constexpr int NG   = KCH * BB;
  constexpr int NB   = 8;            // backward steps for the u direction
  constexpr int NFWD = NG / 256;     // forward blocks (512)
  __shared__ float sE[2][49];        // exp(transitions): [0]=self, [1]=other
  __shared__ float sT[2][49];        // raw transitions (gold-path score)
  int tid = threadIdx.x;
  if (tid < 49) {
    float sv = self_t[tid], ov = other_t[tid];
    sE[0][tid] = __expf(sv); sE[1][tid] = __expf(ov);
    sT[0][tid] = sv;         sT[1][tid] = ov;
  }
  __syncthreads();

  float Es[49];                      // SGPR-resident via readfirstlane
  int loadedCont = -1;
  auto loadEs = [&](int cf) {
#pragma unroll
    for (int k = 0; k < 49; ++k)
      Es[k] = __int_as_float(
          __builtin_amdgcn_readfirstlane(__float_as_int(sE[cf][k])));
    loadedCont = cf;
  };

  int bid = blockIdx.x;
  if (bid < NFWD) {
    // ============ forward: vn, Lmass, gold score (1 chunk/thread) =========
    int g = bid * 256 + tid;
    int b = g & (BB - 1);
    int c = g >> 11;                 // uniform per block (256 | 2048)
    float v[7] = {1.f,1.f,1.f,1.f,1.f,1.f,1.f};
    float sc = 0.f, Lv = 0.f;
    int mc = 0, tp, qp;
    int i0 = c * CC;
    if (c == 0) { mc = mask[b]; tp = tags[b]; qp = qmask[b]; }
    else { size_t pb = (size_t)(i0 - 1) * BB + b; tp = tags[pb]; qp = qmask[pb]; }

    auto LDF = [&](int s, float* e, int& tg, int& qm, int& mi) {
      size_t base = (size_t)(i0 + s) * BB + b;
      ld7(em + base * TT, e);
      tg = tags[base]; qm = qmask[base]; mi = mask[base];
    };

    float e0[7], e1[7];
    int tg0, qm0, mi0, tg1, qm1, mi1;
    LDF(0, e0, tg0, qm0, mi0);

    for (int j = 0; j < CC; ++j) {
      bool more = (j + 1 < CC);                   // wave-uniform
      if (more) LDF(j + 1, e1, tg1, qm1, mi1);    // issue next-step loads

      int mi = (c == 0 && j == 0) ? 0 : mi0;      // boundary step = identity
      int cont = (qm0 != qp) ? 1 : 0;
      int cf = __builtin_amdgcn_readfirstlane(cont);
      bool uni = __all(cont == cf);
      float ee[7];
#pragma unroll
      for (int t = 0; t < 7; ++t) ee[t] = __expf(e0[t]);
      float etag = e0[0];
#pragma unroll
      for (int t = 1; t < 7; ++t) etag = (tg0 == t) ? e0[t] : etag;
      float ttag = sT[cont][tp * 7 + tg0];
      if (mi) { sc += ttag + etag; ++mc; }
      tp = tg0; qp = qm0;

      float a[7] = {0.f,0.f,0.f,0.f,0.f,0.f,0.f};
      if (uni) {
        if (cf != loadedCont) loadEs(cf);
#pragma unroll
        for (int r = 0; r < 7; ++r) {
          float vr = v[r];
#pragma unroll
          for (int t = 0; t < 7; ++t) a[t] = fmaf(vr, Es[r*7+t], a[t]);
        }
      } else {
        loadedCont = -1;
#pragma unroll
        for (int r = 0; r < 7; ++r) {
          float vr = v[r];
#pragma unroll
          for (int t = 0; t < 7; ++t) a[t] = fmaf(vr, sE[cont][r*7+t], a[t]);
        }
      }
#pragma unroll
      for (int t = 0; t < 7; ++t) v[t] = mi ? a[t] * ee[t] : v[t];

      if ((j & 7) == 7) {                         // renorm, track log mass
        float ss = v[0]+v[1]+v[2]+v[3]+v[4]+v[5]+v[6];
        Lv += logf(ss);
        float inv = 1.0f / ss;
#pragma unroll
        for (int t = 0; t < 7; ++t) v[t] *= inv;
      }
      if (more) {
#pragma unroll
        for (int t = 0; t < 7; ++t) e0[t] = e1[t];
        tg0 = tg1; qm0 = qm1; mi0 = mi1;
      }
    }
    float ss = v[0]+v[1]+v[2]+v[3]+v[4]+v[5]+v[6];
    float inv = 1.0f / ss;
#pragma unroll
    for (int t = 0; t < 7; ++t) recs[(size_t)t * NG + g] = v[t] * inv;
    recs[(size_t)14 * NG + g] = sc;
    recs[(size_t)15 * NG + g] = (float)mc;
    recs[(size_t)16 * NG + g] = Lv + logf(ss);    // Lmass = log(1^T P 1)
  } else {
    // ============ backward: u direction, NB steps (1 chunk/thread) ========
    int g = (bid - NFWD) * 256 + tid;
    int b = g & (BB - 1);
    int c = g >> 11;
    float r[7] = {1.f,1.f,1.f,1.f,1.f,1.f,1.f};
    int ilo = (c == 0) ? 1 : c * CC;

    auto LDB = [&](int s, float* e, int& q, int& q1, int& mi2) {
      size_t base = (size_t)(ilo + NB - 1 - s) * BB + b;    // i >= 1
      ld7(em + base * TT, e);
      q = qmask[base]; q1 = qmask[base - BB]; mi2 = mask[base];
    };

    float e0[7], e1[7];
    int q0, q10, m0, q1v, q11, m1;
    LDB(0, e0, q0, q10, m0);

    for (int j = 0; j < NB; ++j) {
      bool more = (j + 1 < NB);
      if (more) LDB(j + 1, e1, q1v, q11, m1);

      int cont = (q0 != q10) ? 1 : 0;
      int cf = __builtin_amdgcn_readfirstlane(cont);
      bool uni = __all(cont == cf);
      float ee[7];
#pragma unroll
      for (int t = 0; t < 7; ++t) ee[t] = __expf(e0[t]);
      float tmp[7];
#pragma unroll
      for (int t = 0; t < 7; ++t) tmp[t] = ee[t] * r[t];
      float a[7] = {0.f,0.f,0.f,0.f,0.f,0.f,0.f};
      if (uni) {
        if (cf != loadedCont) loadEs(cf);
#pragma unroll
        for (int t = 0; t < 7; ++t) {
          float tt = tmp[t];
#pragma unroll
          for (int s2 = 0; s2 < 7; ++s2) a[s2] = fmaf(tt, Es[s2*7+t], a[s2]);
        }
      } else {
        loadedCont = -1;
#pragma unroll
        for (int t = 0; t < 7; ++t) {
          float tt = tmp[t];
#pragma unroll
          for (int s2 = 0; s2 < 7; ++s2) a[s2] = fmaf(tt, sE[cont][s2*7+t], a[s2]);
        }
      }
#pragma unroll
      for (int s2 = 0; s2 < 7; ++s2) r[s2] = m0 ? a[s2] : r[s2];

      if (j == 3) {                               // overflow guard (mid-pass)
        float ss = r[0]+r[1]+r[2]+r[3]+r[4]+r[5]+r[6];
        float inv = 1.0f / ss;
#pragma unroll
        for (int t = 0; t < 7; ++t) r[t] *= inv;
      }
      if (more) {
#pragma unroll
        for (int t = 0; t < 7; ++t) e0[t] = e1[t];
        q0 = q1v; q10 = q11; m0 = m1;
      }
    }
    float ss = r[0]+r[1]+r[2]+r[3]+r[4]+r[5]+r[6];
    float inv = 1.0f / ss;
#pragma unroll
    for (int t = 0; t < 7; ++t) recs[(size_t)(7 + t) * NG + g] = r[t] * inv;
  }
}

// ---------------------------------------------------------------------------
// Kernel 2: flat-parallel junction terms + per-block tree reduction.
// term(b,c) = sc - Lmass - log(dot); dot_0 = alpha0.rn_0 (+gold start terms),
// dot_c = vn_{c-1}.rn_c; c==KCH-1 folds the final logZ term and gold end.
// ---------------------------------------------------------------------------
template<int KCH>
__global__ __launch_bounds__(256)
void crf_junction_kernel(const float* __restrict__ recs,
                         const float* __restrict__ em,
                         const int*   __restrict__ tags,
                         const float* __restrict__ start_t,
                         const float* __restrict__ end_t,
                         float* __restrict__ partials) {
  constexpr int NG = KCH * BB;
  int tid = threadIdx.x;
  int g = blockIdx.x * 256 + tid;
  int b = g & (BB - 1);
  int c = g >> 11;                       // block-uniform (256 | 2048)
  float rn[7];
#pragma unroll
  for (int t = 0; t < 7; ++t) rn[t] = recs[(size_t)(7 + t) * NG + g];
  float term = recs[(size_t)14 * NG + g] - recs[(size_t)16 * NG + g];
  float dot = 0.f;
  if (c == 0) {
    float e0[7], st[7];
#pragma unroll
    for (int t = 0; t < 7; ++t) { e0[t] = em[(size_t)b * TT + t]; st[t] = start_t[t]; }
#pragma unroll
    for (int t = 0; t < 7; ++t) dot = fmaf(__expf(st[t] + e0[t]), rn[t], dot);
    int tg0 = tags[b];
    float em0t = e0[0], stt = st[0];
#pragma unroll
    for (int t = 1; t < 7; ++t) {
      em0t = (tg0 == t) ? e0[t] : em0t;
      stt  = (tg0 == t) ? st[t] : stt;
    }
    term += stt + em0t;                  // gold start + em[0][tag0]
  } else {
#pragma unroll
    for (int t = 0; t < 7; ++t)
      dot = fmaf(recs[(size_t)t * NG + (g - BB)], rn[t], dot);
  }
  term -= logf(dot);
  if (c == KCH - 1) {
    float fz = 0.f;
#pragma unroll
    for (int t = 0; t < 7; ++t)
      fz = fmaf(recs[(size_t)t * NG + g], __expf(end_t[t]), fz);
    term -= logf(fz);                    // final logZ term (own vn)
    float mcf = 0.f;
    for (int cc = 0; cc < KCH; ++cc)
      mcf += recs[(size_t)15 * NG + (size_t)cc * BB + b];
    int se = (int)mcf - 1;
    int te = tags[(size_t)se * BB + b];
    term += end_t[te];                   // gold end transition
  }
  __shared__ float red[256];
  red[tid] = term;
  __syncthreads();
  for (int off = 128; off > 0; off >>= 1) {
    if (tid < off) red[tid] += red[tid + off];
    __syncthreads();
  }
  if (tid == 0) partials[blockIdx.x] = red[0];
}

// ---------------------------------------------------------------------------
// Kernel 3: deterministic tree-reduce of the block partials.
// ---------------------------------------------------------------------------
__global__ __launch_bounds__(1024)
void crf_reduce_kernel(const float* __restrict__ partials, int n,
                       float* __restrict__ out) {
  __shared__ float s[1024];
  int t = threadIdx.x;
  float v = 0.f;
  for (int i = t; i < n; i += 1024) v += partials[i];
  s[t] = v;
  __syncthreads();
  for (int off = 512; off > 0; off >>= 1) {
    if (t < off) s[t] += s[t + off];
    __syncthreads();
  }
  if (t == 0) out[0] = s[0];
}

extern "C" void kernel_launch(void* const* d_in, const int* in_sizes, int n_in,
                              void* d_out, int out_size, void* d_ws, size_t ws_size,
                              hipStream_t stream) {
  const float* em      = (const float*)d_in[0];
  const int*   tags    = (const int*)d_in[1];
  const int*   qmask   = (const int*)d_in[2];
  const int*   mask    = (const int*)d_in[3];
  const float* start_t = (const float*)d_in[4];
  const float* end_t   = (const float*)d_in[5];
  const float* self_t  = (const float*)d_in[6];
  const float* other_t = (const float*)d_in[7];

  float* recs = (float*)d_ws;

  constexpr int KCH = 64;     // CC=32; ws need ~8.9 MB
  constexpr int NG  = KCH * BB;
  float* partials = recs + (size_t)NFLD * NG;

  int fwd_blocks = NG / 256;          // 512 (2048 waves, 32 steps each)
  int bwd_blocks = NG / 256;          // 512 (2048... waves? no: 1 chunk/thread)
  crf_chunk_kernel<KCH><<<fwd_blocks + bwd_blocks, 256, 0, stream>>>(
      em, tags, qmask, mask, self_t, other_t, recs);
  crf_junction_kernel<KCH><<<NG / 256, 256, 0, stream>>>(
      recs, em, tags, start_t, end_t, partials);
  crf_reduce_kernel<<<1, 1024, 0, stream>>>(partials, NG / 256, (float*)d_out);
}